// Round 1
// baseline (371.001 us; speedup 1.0000x reference)
//
#include <hip/hip_runtime.h>

#define TT 512
#define BB 64
#define DD 1024
#define KK 32

// ---------------------------------------------------------------------------
// Kernel 1: emission.  F[m,k] = exp( x[m,:] @ W[:,k] + b[k] ),  m = b*T + t.
// Tile: 64 rows/block, 256 threads: kg = t&7 (4 k's), rg = t>>3 (2 rows).
// W staged in LDS in 64-d chunks (8 KB).
// ---------------------------------------------------------------------------
__global__ __launch_bounds__(256) void emit_kernel(
    const float* __restrict__ x, const float* __restrict__ W,
    const float* __restrict__ bias, float* __restrict__ F) {
  __shared__ __align__(16) float Ws[64 * KK];
  const int t = threadIdx.x;
  const int kg = t & 7;
  const int rg = t >> 3;
  const int m0 = blockIdx.x * 64;
  const float* x0 = x + (size_t)(m0 + rg * 2) * DD;
  const float* x1 = x0 + DD;
  float acc[2][4];
#pragma unroll
  for (int r = 0; r < 2; ++r)
#pragma unroll
    for (int c = 0; c < 4; ++c) acc[r][c] = 0.f;

  for (int d0 = 0; d0 < DD; d0 += 64) {
    __syncthreads();
    const float4* Wg = (const float4*)(W + d0 * KK);
    float4* Wl = (float4*)Ws;
    Wl[t] = Wg[t];
    Wl[t + 256] = Wg[t + 256];
    __syncthreads();
#pragma unroll
    for (int dq = 0; dq < 64; dq += 4) {
      float4 xa = *(const float4*)(x0 + d0 + dq);
      float4 xb = *(const float4*)(x1 + d0 + dq);
      float4 w0 = *(const float4*)&Ws[(dq + 0) * KK + kg * 4];
      float4 w1 = *(const float4*)&Ws[(dq + 1) * KK + kg * 4];
      float4 w2 = *(const float4*)&Ws[(dq + 2) * KK + kg * 4];
      float4 w3 = *(const float4*)&Ws[(dq + 3) * KK + kg * 4];
      acc[0][0] += xa.x*w0.x + xa.y*w1.x + xa.z*w2.x + xa.w*w3.x;
      acc[0][1] += xa.x*w0.y + xa.y*w1.y + xa.z*w2.y + xa.w*w3.y;
      acc[0][2] += xa.x*w0.z + xa.y*w1.z + xa.z*w2.z + xa.w*w3.z;
      acc[0][3] += xa.x*w0.w + xa.y*w1.w + xa.z*w2.w + xa.w*w3.w;
      acc[1][0] += xb.x*w0.x + xb.y*w1.x + xb.z*w2.x + xb.w*w3.x;
      acc[1][1] += xb.x*w0.y + xb.y*w1.y + xb.z*w2.y + xb.w*w3.y;
      acc[1][2] += xb.x*w0.z + xb.y*w1.z + xb.z*w2.z + xb.w*w3.z;
      acc[1][3] += xb.x*w0.w + xb.y*w1.w + xb.z*w2.w + xb.w*w3.w;
    }
  }
  float4 bv = *(const float4*)(bias + kg * 4);
#pragma unroll
  for (int r = 0; r < 2; ++r) {
    float4 o;
    o.x = __expf(acc[r][0] + bv.x);
    o.y = __expf(acc[r][1] + bv.y);
    o.z = __expf(acc[r][2] + bv.z);
    o.w = __expf(acc[r][3] + bv.w);
    *(float4*)(F + (size_t)(m0 + rg * 2 + r) * KK + kg * 4) = o;
  }
}

// ---------------------------------------------------------------------------
// Kernel 2: scaled linear-domain forward/backward recursions.
// One wave (64 lanes) per chain; blocks 0..63 = forward batch b,
// blocks 64..127 = backward batch b-64.  Lane = (kk = l&31, h = l>>5).
//   fwd: A_t[k] = (sum_j A_{t-1}[j] * V[j,k]) * F_t[k] * rcp(A_{t-1}[0])
//   bwd: B_t[j] = (sum_k V[j,k] * g[k]) * rcp(g[0]),  g = B_{t+1} ∘ F_{t+1}
// Per-(t) scale factors cancel exactly in the final per-row softmax.
// ---------------------------------------------------------------------------
__global__ __launch_bounds__(64) void scan_kernel(
    const float* __restrict__ F, const float* __restrict__ U,
    float* __restrict__ A, float* __restrict__ Bw) {
  __shared__ __align__(16) float cur[KK];
  const int l = threadIdx.x;
  const int kk = l & 31;
  const int h = l >> 5;
  const int bid = blockIdx.x;

  float V[16];
  if (bid < BB) {
    // ---------------- forward ----------------
    const int b = bid;
#pragma unroll
    for (int j = 0; j < 16; ++j) V[j] = __expf(U[(h * 16 + j) * KK + kk]);
    const float* Fb = F + (size_t)b * TT * KK;
    float* Ab = A + (size_t)b * TT * KK;
    float a0 = Fb[kk];
    if (l < 32) { Ab[kk] = a0; cur[kk] = a0; }
    __syncthreads();
    float Fv = Fb[1 * KK + kk];
    for (int t = 1; t < TT; ++t) {
      float Fnext = (t + 1 < TT) ? Fb[(t + 1) * KK + kk] : 0.f;
      float r = __builtin_amdgcn_rcpf(cur[0]);
      const float4* c4 = (const float4*)cur;
      float4 y0 = c4[h * 4 + 0];
      float4 y1 = c4[h * 4 + 1];
      float4 y2 = c4[h * 4 + 2];
      float4 y3 = c4[h * 4 + 3];
      float s = y0.x*V[0]  + y0.y*V[1]  + y0.z*V[2]  + y0.w*V[3]
              + y1.x*V[4]  + y1.y*V[5]  + y1.z*V[6]  + y1.w*V[7]
              + y2.x*V[8]  + y2.y*V[9]  + y2.z*V[10] + y2.w*V[11]
              + y3.x*V[12] + y3.y*V[13] + y3.z*V[14] + y3.w*V[15];
      s += __shfl_xor(s, 32);
      float anew = s * Fv * r;
      if (l < 32) { Ab[t * KK + kk] = anew; cur[kk] = anew; }
      Fv = Fnext;
      __syncthreads();
    }
  } else {
    // ---------------- backward ----------------
    const int b = bid - BB;
#pragma unroll
    for (int j = 0; j < 16; ++j) V[j] = __expf(U[kk * KK + h * 16 + j]);
    const float* Fb = F + (size_t)b * TT * KK;
    float* Bb = Bw + (size_t)b * TT * KK;
    if (l < 32) {
      Bb[(TT - 1) * KK + kk] = 1.0f;
      cur[kk] = Fb[(TT - 1) * KK + kk];  // g_{T-1} = B_{T-1} ∘ F_{T-1}
    }
    __syncthreads();
    float Fv = Fb[(TT - 2) * KK + kk];
    for (int t = TT - 2; t >= 0; --t) {
      float Fnext = (t > 0) ? Fb[(t - 1) * KK + kk] : 0.f;
      float r = __builtin_amdgcn_rcpf(cur[0]);
      const float4* c4 = (const float4*)cur;
      float4 y0 = c4[h * 4 + 0];
      float4 y1 = c4[h * 4 + 1];
      float4 y2 = c4[h * 4 + 2];
      float4 y3 = c4[h * 4 + 3];
      float s = y0.x*V[0]  + y0.y*V[1]  + y0.z*V[2]  + y0.w*V[3]
              + y1.x*V[4]  + y1.y*V[5]  + y1.z*V[6]  + y1.w*V[7]
              + y2.x*V[8]  + y2.y*V[9]  + y2.z*V[10] + y2.w*V[11]
              + y3.x*V[12] + y3.y*V[13] + y3.z*V[14] + y3.w*V[15];
      s += __shfl_xor(s, 32);
      float bnew = s * r;
      float gnew = bnew * Fv;  // g_t = B_t ∘ F_t
      if (l < 32) { Bb[t * KK + kk] = bnew; cur[kk] = gnew; }
      Fv = Fnext;
      __syncthreads();
    }
  }
}

// ---------------------------------------------------------------------------
// Kernel 3: marginals.  out[m,k] = A[m,k]*B[m,k] / sum_k' A[m,k']*B[m,k'].
// A lives in d_out (in-place).  K=32 groups align with 32-lane half-waves.
// ---------------------------------------------------------------------------
__global__ __launch_bounds__(256) void combine_kernel(
    const float* __restrict__ Bw, float* __restrict__ out) {
  size_t i = (size_t)blockIdx.x * 256 + threadIdx.x;
  float p = out[i] * Bw[i];
  float ssum = p;
  ssum += __shfl_xor(ssum, 1);
  ssum += __shfl_xor(ssum, 2);
  ssum += __shfl_xor(ssum, 4);
  ssum += __shfl_xor(ssum, 8);
  ssum += __shfl_xor(ssum, 16);
  out[i] = p / ssum;
}

extern "C" void kernel_launch(void* const* d_in, const int* in_sizes, int n_in,
                              void* d_out, int out_size, void* d_ws, size_t ws_size,
                              hipStream_t stream) {
  const float* x = (const float*)d_in[0];   // [B,T,D]
  const float* W = (const float*)d_in[1];   // [D,K]
  const float* U = (const float*)d_in[2];   // [K,K]
  const float* b = (const float*)d_in[3];   // [K]
  float* out = (float*)d_out;               // [B,T,K] — doubles as A scratch
  float* F = (float*)d_ws;                  // exp(emissions), [B*T, K] (4 MB)
  float* Bw = F + (size_t)BB * TT * KK;     // backward messages    (4 MB)

  emit_kernel<<<(BB * TT) / 64, 256, 0, stream>>>(x, W, b, F);
  scan_kernel<<<2 * BB, 64, 0, stream>>>(F, U, out, Bw);
  combine_kernel<<<(BB * TT * KK) / 256, 256, 0, stream>>>(Bw, out);
}